// Round 1
// baseline (208.050 us; speedup 1.0000x reference)
//
#include <hip/hip_runtime.h>
#include <math.h>

#define BATCH 32
#define CH 768
#define HW 3136           // 56*56
#define HW4 (HW/4)        // 784 float4 per plane
#define HID 48
#define PLANES (BATCH*CH) // 24576

// ---------------- Kernel 1: per-plane avg + max pooling ----------------
__global__ __launch_bounds__(256) void cbam_pool(const float* __restrict__ x,
                                                 float* __restrict__ avg,
                                                 float* __restrict__ mx) {
    const int plane = blockIdx.x;
    const float4* xp = reinterpret_cast<const float4*>(x + (size_t)plane * HW);

    float s = 0.0f;
    float m = -INFINITY;
    for (int i = threadIdx.x; i < HW4; i += 256) {
        float4 v = xp[i];
        s += v.x + v.y + v.z + v.w;
        m = fmaxf(m, fmaxf(fmaxf(v.x, v.y), fmaxf(v.z, v.w)));
    }
    // wave (64-lane) butterfly reduce
    for (int off = 32; off > 0; off >>= 1) {
        s += __shfl_down(s, off, 64);
        m = fmaxf(m, __shfl_down(m, off, 64));
    }
    __shared__ float ss[4];
    __shared__ float sm[4];
    const int wave = threadIdx.x >> 6;
    if ((threadIdx.x & 63) == 0) { ss[wave] = s; sm[wave] = m; }
    __syncthreads();
    if (threadIdx.x == 0) {
        float fs = ss[0] + ss[1] + ss[2] + ss[3];
        float fm = fmaxf(fmaxf(sm[0], sm[1]), fmaxf(sm[2], sm[3]));
        avg[plane] = fs * (1.0f / (float)HW);
        mx[plane]  = fm;
    }
}

// ---------------- Kernel 2: shared-MLP + sigmoid gate ----------------
// gate[b,c] = sigmoid( sum_h (gelu(avg_b . w1_h) + gelu(max_b . w1_h)) * w2[c,h] )
__global__ __launch_bounds__(256) void cbam_mlp(const float* __restrict__ avg,
                                                const float* __restrict__ mx,
                                                const float* __restrict__ w1,   // [HID, CH]
                                                const float* __restrict__ w2,   // [CH, HID]
                                                float* __restrict__ gate) {
    const int b = blockIdx.x;
    __shared__ float sa[CH];
    __shared__ float sv[CH];
    __shared__ float ha[HID];
    __shared__ float hm[HID];
    __shared__ float hsum[HID];

    for (int i = threadIdx.x; i < CH; i += 256) {
        sa[i] = avg[b * CH + i];
        sv[i] = mx[b * CH + i];
    }
    __syncthreads();

    // hidden layer: threads 0..47 -> avg branch, 48..95 -> max branch
    if (threadIdx.x < 2 * HID) {
        const bool is_avg = threadIdx.x < HID;
        const int h = is_avg ? threadIdx.x : threadIdx.x - HID;
        const float* in = is_avg ? sa : sv;
        const float* wr = w1 + (size_t)h * CH;
        float acc = 0.0f;
        #pragma unroll 8
        for (int k = 0; k < CH; ++k) acc += in[k] * wr[k];
        // exact GELU (erf form)
        float g = 0.5f * acc * (1.0f + erff(acc * 0.70710678118654752f));
        if (is_avg) ha[h] = g; else hm[h] = g;
    }
    __syncthreads();
    if (threadIdx.x < HID) hsum[threadIdx.x] = ha[threadIdx.x] + hm[threadIdx.x];
    __syncthreads();

    // output layer + sigmoid
    for (int c = threadIdx.x; c < CH; c += 256) {
        const float* wr = w2 + (size_t)c * HID;
        float acc = 0.0f;
        #pragma unroll
        for (int h = 0; h < HID; ++h) acc += hsum[h] * wr[h];
        gate[b * CH + c] = 1.0f / (1.0f + expf(-acc));
    }
}

// ---------------- Kernel 3: scale x by gate ----------------
__global__ __launch_bounds__(256) void cbam_scale(const float* __restrict__ x,
                                                  const float* __restrict__ gate,
                                                  float* __restrict__ out) {
    const int plane = blockIdx.x;            // wave-uniform
    const float g = gate[plane];             // scalar-cached broadcast
    const float4* xp = reinterpret_cast<const float4*>(x + (size_t)plane * HW);
    float4* op = reinterpret_cast<float4*>(out + (size_t)plane * HW);
    for (int i = threadIdx.x; i < HW4; i += 256) {
        float4 v = xp[i];
        v.x *= g; v.y *= g; v.z *= g; v.w *= g;
        op[i] = v;
    }
}

extern "C" void kernel_launch(void* const* d_in, const int* in_sizes, int n_in,
                              void* d_out, int out_size, void* d_ws, size_t ws_size,
                              hipStream_t stream) {
    const float* x  = (const float*)d_in[0];
    const float* w1 = (const float*)d_in[1];
    const float* w2 = (const float*)d_in[2];
    float* out = (float*)d_out;

    float* avg  = (float*)d_ws;              // PLANES floats
    float* mx   = avg + PLANES;              // PLANES floats
    float* gate = mx + PLANES;               // PLANES floats

    cbam_pool<<<PLANES, 256, 0, stream>>>(x, avg, mx);
    cbam_mlp<<<BATCH, 256, 0, stream>>>(avg, mx, w1, w2, gate);
    cbam_scale<<<PLANES, 256, 0, stream>>>(x, gate, out);
}

// Round 4
// 175.677 us; speedup vs baseline: 1.1843x; 1.1843x over previous
//
#include <hip/hip_runtime.h>
#include <math.h>

#define BATCH 32
#define CH 768
#define HW 3136           // 56*56
#define HW4 (HW/4)        // 784 float4 per plane
#define HID 48
#define PLANES (BATCH*CH) // 24576
#define WPB 4             // waves per block (256 threads)

typedef float nfloat4 __attribute__((ext_vector_type(4)));   // clang-native vec for nontemporal builtins

// ---------------- Kernel 1: per-plane avg + max pooling (wave per plane) ----------------
__global__ __launch_bounds__(256) void cbam_pool(const float* __restrict__ x,
                                                 float* __restrict__ avg,
                                                 float* __restrict__ mx) {
    const int wave = threadIdx.x >> 6;
    const int lane = threadIdx.x & 63;
    const int plane = blockIdx.x * WPB + wave;
    const nfloat4* xp = reinterpret_cast<const nfloat4*>(x + (size_t)plane * HW);

    float s = 0.0f;
    float m = -INFINITY;
    for (int i = lane; i < HW4; i += 64) {
        nfloat4 v = xp[i];
        s += (v.x + v.y) + (v.z + v.w);
        m = fmaxf(m, fmaxf(fmaxf(v.x, v.y), fmaxf(v.z, v.w)));
    }
    // 64-lane butterfly reduce (wave-local, no LDS)
    for (int off = 32; off > 0; off >>= 1) {
        s += __shfl_down(s, off, 64);
        m = fmaxf(m, __shfl_down(m, off, 64));
    }
    if (lane == 0) {
        avg[plane] = s * (1.0f / (float)HW);
        mx[plane]  = m;
    }
}

// ---------------- Kernel 2: shared-MLP + sigmoid gate (all barriers wave-uniform) ----------------
__global__ __launch_bounds__(256) void cbam_mlp(const float* __restrict__ avg,
                                                const float* __restrict__ mx,
                                                const float* __restrict__ w1,   // [HID, CH]
                                                const float* __restrict__ w2,   // [CH, HID]
                                                float* __restrict__ gate) {
    const int b = blockIdx.x;
    __shared__ float sa[CH];
    __shared__ float sv[CH];
    __shared__ float ha[HID];
    __shared__ float hm[HID];
    __shared__ float hsum[HID];

    for (int i = threadIdx.x; i < CH; i += 256) {
        sa[i] = avg[b * CH + i];
        sv[i] = mx[b * CH + i];
    }
    __syncthreads();

    // hidden layer: threads 0..47 -> avg branch, 48..95 -> max branch (float4 loads)
    if (threadIdx.x < 2 * HID) {
        const bool is_avg = threadIdx.x < HID;
        const int h = is_avg ? threadIdx.x : threadIdx.x - HID;
        const float4* in4 = reinterpret_cast<const float4*>(is_avg ? sa : sv);
        const float4* wr4 = reinterpret_cast<const float4*>(w1 + (size_t)h * CH);
        float acc = 0.0f;
        #pragma unroll 8
        for (int k = 0; k < CH / 4; ++k) {
            float4 a = in4[k];
            float4 w = wr4[k];
            acc += a.x * w.x + a.y * w.y + a.z * w.z + a.w * w.w;
        }
        // exact GELU (erf form)
        float g = 0.5f * acc * (1.0f + erff(acc * 0.70710678118654752f));
        if (is_avg) ha[h] = g; else hm[h] = g;
    }
    __syncthreads();
    if (threadIdx.x < HID) hsum[threadIdx.x] = ha[threadIdx.x] + hm[threadIdx.x];
    __syncthreads();

    // output layer + sigmoid
    for (int c = threadIdx.x; c < CH; c += 256) {
        const float4* wr4 = reinterpret_cast<const float4*>(w2 + (size_t)c * HID);
        const float4* hs4 = reinterpret_cast<const float4*>(hsum);
        float acc = 0.0f;
        #pragma unroll
        for (int h = 0; h < HID / 4; ++h) {
            float4 a = hs4[h];
            float4 w = wr4[h];
            acc += a.x * w.x + a.y * w.y + a.z * w.z + a.w * w.w;
        }
        gate[b * CH + c] = 1.0f / (1.0f + expf(-acc));
    }
}

// ---------------- Kernel 3: scale x by gate (wave per plane, REVERSE order for L3 reuse) ----------------
__global__ __launch_bounds__(256) void cbam_scale(const float* __restrict__ x,
                                                  const float* __restrict__ gate,
                                                  float* __restrict__ out) {
    const int wave = threadIdx.x >> 6;
    const int lane = threadIdx.x & 63;
    // earliest blocks touch the planes pool read LAST (hottest in L3)
    const int plane = (PLANES - 1) - (blockIdx.x * WPB + wave);
    const float g = gate[plane];
    const nfloat4* xp = reinterpret_cast<const nfloat4*>(x + (size_t)plane * HW);
    nfloat4* op = reinterpret_cast<nfloat4*>(out + (size_t)plane * HW);
    for (int i = lane; i < HW4; i += 64) {
        nfloat4 v = xp[i];
        v.x *= g; v.y *= g; v.z *= g; v.w *= g;
        __builtin_nontemporal_store(v, &op[i]);   // don't let out-writes evict x from L3
    }
}

extern "C" void kernel_launch(void* const* d_in, const int* in_sizes, int n_in,
                              void* d_out, int out_size, void* d_ws, size_t ws_size,
                              hipStream_t stream) {
    const float* x  = (const float*)d_in[0];
    const float* w1 = (const float*)d_in[1];
    const float* w2 = (const float*)d_in[2];
    float* out = (float*)d_out;

    float* avg  = (float*)d_ws;              // PLANES floats
    float* mx   = avg + PLANES;              // PLANES floats
    float* gate = mx + PLANES;               // PLANES floats

    cbam_pool<<<PLANES / WPB, 256, 0, stream>>>(x, avg, mx);
    cbam_mlp<<<BATCH, 256, 0, stream>>>(avg, mx, w1, w2, gate);
    cbam_scale<<<PLANES / WPB, 256, 0, stream>>>(x, gate, out);
}